// Round 8
// baseline (419.651 us; speedup 1.0000x reference)
//
#include <hip/hip_runtime.h>
#include <hip/hip_bf16.h>
#include <stdint.h>

// MultiHeadedSelfAttention: B=2, L=4096, D=1024, H=1. fp32 inputs, FP32 output.
// Round 20: fixes round-19's correctness bug — JF must be BN/32 (fragments
// per wave N-half = (BN/2)/16), not BN/64. Round-19 only wrote half the
// columns of every tile (absmax 2.6). Design otherwise unchanged:
// (a) depth-3 prefetch everywhere (48KiB LDS free at VGPR-capped 3/CU);
// (b) thin-tile BN=64 for PV and final (grid 1024, acc 32 AGPR -> 4/CU);
// (c) XCD swizzle on QKp/scores/PV/final, Vt natural.
// Pipeline:
//   0. cast x, Wq, Wk, Wv, Wo -> bf16 (once)
//   1. QKp = x @ [Wq;Wk]^T    (8192x2048, K=1024)  grid 1024  [<1,128>]
//   2. Vt  = Wv @ x^T          (1024x8192)          grid 512   [<0,128>]
//   3. S_z = Q_z @ Kp_z^T/32   (2x 4096x4096)       grid 2048  [<1,128>]
//   4. softmax rows (8192 rows)
//   5. O_z = P_z @ V_z         -> O into QKp region grid 1024  [<1,64>]
//   6. out = O @ Wo^T -> FP32 d_out                 grid 1024  [<1,64>]
// ws (u16): xb 8.39M | W*b 4x1.05M | QKp 16.78M | Vt 8.39M | S 33.55M
// = 71,303,168 u16 = 136 MiB (layout proven safe in prior rounds).

typedef unsigned short u16;
typedef short short8 __attribute__((ext_vector_type(8)));
typedef float f32x4 __attribute__((ext_vector_type(4)));

__device__ __forceinline__ void async_ld16(void* lds, const void* g) {
  __builtin_amdgcn_global_load_lds(
      (const __attribute__((address_space(1))) unsigned int*)g,
      (__attribute__((address_space(3))) unsigned int*)lds,
      16, 0, 0);
}

__device__ __forceinline__ u16 f2bf(float f) {  // RNE
  unsigned u = __float_as_uint(f);
  u += 0x7FFFu + ((u >> 16) & 1u);
  return (u16)(u >> 16);
}

// fp32 -> bf16, 8 elems/thread. n must be a multiple of 8 (true here).
__global__ __launch_bounds__(256)
void cast_f32_bf16(const float* __restrict__ in, u16* __restrict__ out, int n) {
  const int i = (blockIdx.x * 256 + threadIdx.x) * 8;
  if (i >= n) return;
  float4 a = ((const float4*)(in + i))[0];
  float4 b = ((const float4*)(in + i))[1];
  uint4 o;
  o.x = (unsigned)f2bf(a.x) | ((unsigned)f2bf(a.y) << 16);
  o.y = (unsigned)f2bf(a.z) | ((unsigned)f2bf(a.w) << 16);
  o.z = (unsigned)f2bf(b.x) | ((unsigned)f2bf(b.y) << 16);
  o.w = (unsigned)f2bf(b.z) | ((unsigned)f2bf(b.w) << 16);
  *(uint4*)(out + i) = o;
}

#define BM 128
#define BK 32

// C(MxN, ldc) = scale * A(MxK, lda) @ Bt(NxK, ldb)^T. A,Bt bf16; fp32 accum.
// Triple-buffered LDS, depth-3 prefetch, counted vmcnt(2L/L/0) where
// L = loads/tile (4 for BN=128, 3 for BN=64). 4 waves in 2x2; wave tile is
// 64 x (BN/2) covered by JF = BN/32 column fragments of 16.
// XSWZ=1 adds bijective XCD block swizzle (needs nwg % 8 == 0).
// Buffer discipline (round-4-proven): stage(kt)->buf[kt%3]; top of kt:
// counted vmcnt + barrier; reads+MFMA; end barrier; stage(kt+3) into the
// same-index buffer just fully read.
template <int XSWZ, int BN>
__global__ __launch_bounds__(256)
void gemm_bt(const u16* __restrict__ A, const u16* __restrict__ Bt,
             void* __restrict__ Cv, int K, int lda, int ldb, int ldc,
             long long sAz, long long sBz, long long sCz,
             float scale, int store_f32) {
  constexpr int JF = BN / 32;           // fragments per wave N-half (4 or 2)
  __shared__ u16 As[3][BM * BK];
  __shared__ u16 Bs[3][BN * BK];

  int bx, by, bz;
  if constexpr (XSWZ) {
    const int gx = gridDim.x, gy = gridDim.y;
    const int nwg = gx * gy * gridDim.z;
    const int lin = (blockIdx.z * gy + blockIdx.y) * gx + blockIdx.x;
    const int chunk = nwg >> 3;
    const int swz = (lin & 7) * chunk + (lin >> 3);
    bx = swz % gx;
    const int t1 = swz / gx;
    by = t1 % gy;
    bz = t1 / gy;
  } else {
    bx = blockIdx.x; by = blockIdx.y; bz = blockIdx.z;
  }

  A  += (long long)bz * sAz;
  Bt += (long long)bz * sBz;

  const int tid  = threadIdx.x;
  const int wave = tid >> 6;
  const int lane = tid & 63;
  const int wm   = wave >> 1;      // 0..1: wave row in 2x2
  const int wn   = wave & 1;       // 0..1: wave col
  const int r15  = lane & 15;
  const int q4   = lane >> 4;      // 0..3

  const int tileM = by * BM;
  const int tileN = bx * BN;

  const int srow = tid >> 2;                        // 0..63
  const int scol = ((tid & 3) ^ (srow & 3)) * 8;    // pre-swizzled source col

  const u16* Aptr = A + (long long)tileM * lda + scol;
  const u16* Bptr = Bt + (long long)tileN * ldb + scol;

  // stage K-tile kt into buf[kt%3]. Loads/tile: A 2 + B (BN/64).
  auto stage = [&](int kt) {
    const int b = kt % 3;
    const int k0 = kt * BK;
    u16* as = &As[b][tid * 8];
    u16* bs = &Bs[b][tid * 8];
    async_ld16(as,        Aptr + (long long)srow * lda + k0);
    async_ld16(as + 2048, Aptr + (long long)(srow + 64) * lda + k0);
    async_ld16(bs,        Bptr + (long long)srow * ldb + k0);
    if constexpr (BN == 128)
      async_ld16(bs + 2048, Bptr + (long long)(srow + 64) * ldb + k0);
  };

  f32x4 zero = {0.f, 0.f, 0.f, 0.f};
  f32x4 acc[4][JF];
#pragma unroll
  for (int i = 0; i < 4; ++i)
#pragma unroll
    for (int j = 0; j < JF; ++j) acc[i][j] = zero;

  // read col-chunk (permutation matching the staged layout)
  const int csw = ((q4 ^ (r15 & 3)) * 8);

  const int NT = K / BK;
  stage(0);
  if (NT > 1) stage(1);
  if (NT > 2) stage(2);

  for (int kt = 0; kt < NT; ++kt) {
    const int rem = NT - 1 - kt;
    if constexpr (BN == 128) {
      if (rem >= 2)      asm volatile("s_waitcnt vmcnt(8)" ::: "memory");
      else if (rem == 1) asm volatile("s_waitcnt vmcnt(4)" ::: "memory");
      else               asm volatile("s_waitcnt vmcnt(0)" ::: "memory");
    } else {
      if (rem >= 2)      asm volatile("s_waitcnt vmcnt(6)" ::: "memory");
      else if (rem == 1) asm volatile("s_waitcnt vmcnt(3)" ::: "memory");
      else               asm volatile("s_waitcnt vmcnt(0)" ::: "memory");
    }
    __builtin_amdgcn_s_barrier();

    const int b = kt % 3;
    const u16* as = &As[b][0];
    const u16* bs = &Bs[b][0];

    short8 af[4], bf[JF];
#pragma unroll
    for (int i = 0; i < 4; ++i)
      af[i] = *(const short8*)&as[(wm * 64 + i * 16 + r15) * BK + csw];
#pragma unroll
    for (int j = 0; j < JF; ++j)
      bf[j] = *(const short8*)&bs[(wn * (BN / 2) + j * 16 + r15) * BK + csw];

    __builtin_amdgcn_s_setprio(1);
#pragma unroll
    for (int i = 0; i < 4; ++i)
#pragma unroll
      for (int j = 0; j < JF; ++j)
        acc[i][j] = __builtin_amdgcn_mfma_f32_16x16x32_bf16(af[i], bf[j], acc[i][j], 0, 0, 0);
    __builtin_amdgcn_s_setprio(0);

    __builtin_amdgcn_s_barrier();
    if (kt + 3 < NT) stage(kt + 3);   // into buf[kt%3], fully read past barrier
  }

  // epilogue: C/D layout col = lane&15, row = q4*4 + reg  [e2e-verified]
#pragma unroll
  for (int i = 0; i < 4; ++i) {
#pragma unroll
    for (int j = 0; j < JF; ++j) {
      const int col = tileN + wn * (BN / 2) + j * 16 + r15;
#pragma unroll
      for (int r = 0; r < 4; ++r) {
        const int row = tileM + wm * 64 + i * 16 + q4 * 4 + r;
        const long long idx = (long long)bz * sCz + (long long)row * ldc + col;
        const float val = acc[i][j][r] * scale;
        if (store_f32) ((float*)Cv)[idx] = val;
        else           ((u16*)Cv)[idx] = f2bf(val);
      }
    }
  }
}

// In-place row softmax over 4096 bf16 columns. grid = rows, block = 256.
__global__ __launch_bounds__(256)
void softmax_rows(u16* __restrict__ S) {
  const int tid = threadIdx.x;
  u16* rp = S + (long long)blockIdx.x * 4096;

  uint4 a = ((const uint4*)rp)[tid * 2];
  uint4 b = ((const uint4*)rp)[tid * 2 + 1];
  unsigned w[8] = {a.x, a.y, a.z, a.w, b.x, b.y, b.z, b.w};
  float v[16];
#pragma unroll
  for (int i = 0; i < 8; ++i) {
    v[2 * i]     = __uint_as_float(w[i] << 16);
    v[2 * i + 1] = __uint_as_float(w[i] & 0xFFFF0000u);
  }

  float m = v[0];
#pragma unroll
  for (int i = 1; i < 16; ++i) m = fmaxf(m, v[i]);
#pragma unroll
  for (int o = 32; o > 0; o >>= 1) m = fmaxf(m, __shfl_xor(m, o));
  __shared__ float redm[4];
  __shared__ float reds[4];
  const int wave = tid >> 6;
  if ((tid & 63) == 0) redm[wave] = m;
  __syncthreads();
  m = fmaxf(fmaxf(redm[0], redm[1]), fmaxf(redm[2], redm[3]));

  float s = 0.f;
#pragma unroll
  for (int i = 0; i < 16; ++i) {
    v[i] = __expf(v[i] - m);
    s += v[i];
  }
#pragma unroll
  for (int o = 32; o > 0; o >>= 1) s += __shfl_xor(s, o);
  if ((tid & 63) == 0) reds[wave] = s;
  __syncthreads();
  s = (reds[0] + reds[1]) + (reds[2] + reds[3]);
  const float inv = 1.0f / s;

#pragma unroll
  for (int i = 0; i < 8; ++i)
    w[i] = (unsigned)f2bf(v[2 * i] * inv) | ((unsigned)f2bf(v[2 * i + 1] * inv) << 16);
  uint4 oa = {w[0], w[1], w[2], w[3]};
  uint4 ob = {w[4], w[5], w[6], w[7]};
  ((uint4*)rp)[tid * 2] = oa;
  ((uint4*)rp)[tid * 2 + 1] = ob;
}

extern "C" void kernel_launch(void* const* d_in, const int* in_sizes, int n_in,
                              void* d_out, int out_size, void* d_ws, size_t ws_size,
                              hipStream_t stream) {
  const float* x  = (const float*)d_in[0];   // (2,4096,1024) fp32, batch-major
  const float* Wq = (const float*)d_in[1];   // (1024,1024) fp32 (out,in)
  const float* Wk = (const float*)d_in[2];
  const float* Wv = (const float*)d_in[3];
  const float* Wo = (const float*)d_in[4];
  float* out = (float*)d_out;                // (2,4096,1024) FP32

  // ws layout (u16 units) — 136 MiB total
  u16* xb  = (u16*)d_ws;                     // 8192x1024
  u16* Wqb = xb  + 8388608;                  // 1024x1024
  u16* Wkb = Wqb + 1048576;                  // contiguous after Wqb!
  u16* Wvb = Wkb + 1048576;
  u16* Wob = Wvb + 1048576;
  u16* QKp = Wob + 1048576;                  // 8192x2048: Q cols 0-1023, Kp 1024+
  u16* Vt  = QKp + 16777216;                 // 1024x8192 (Vt[e][b*4096+l])
  u16* S   = Vt  + 8388608;                  // 2 x 4096x4096
  u16* O   = QKp;                            // alias: QKp dead after scores GEMM

  const dim3 blk(256);

  // 0: casts (once)
  cast_f32_bf16<<<dim3(4096), blk, 0, stream>>>(x,  xb,  8388608);
  cast_f32_bf16<<<dim3(512),  blk, 0, stream>>>(Wq, Wqb, 1048576);
  cast_f32_bf16<<<dim3(512),  blk, 0, stream>>>(Wk, Wkb, 1048576);
  cast_f32_bf16<<<dim3(512),  blk, 0, stream>>>(Wv, Wvb, 1048576);
  cast_f32_bf16<<<dim3(512),  blk, 0, stream>>>(Wo, Wob, 1048576);

  // 1: QKp = x @ [Wq;Wk]^T   (M=8192, N=2048, K=1024), 1024 blocks, XCD-swz
  gemm_bt<1, 128><<<dim3(16, 64, 1), blk, 0, stream>>>(xb, Wqb, QKp,
                                                       1024, 1024, 1024, 2048,
                                                       0, 0, 0, 1.f, 0);
  // 2: Vt = Wv@x^T   (M=1024, N=8192, K=1024) -> ldc=8192, 512 blocks.
  //    NO swizzle: natural lin%8=bx%8 already groups same-B-panel per XCD.
  gemm_bt<0, 128><<<dim3(64, 8, 1), blk, 0, stream>>>(Wvb, xb, Vt,
                                                      1024, 1024, 1024, 8192,
                                                      0, 0, 0, 1.f, 0);
  // 3: S_z = Q_z @ Kp_z^T / 32   (M=N=4096, K=1024), z=2 — 2048 blocks, XCD-swz
  gemm_bt<1, 128><<<dim3(32, 32, 2), blk, 0, stream>>>(QKp, QKp + 1024, S,
                                                       1024, 2048, 2048, 4096,
                                                       8388608LL, 8388608LL,
                                                       16777216LL, 0.03125f, 0);
  // 4: softmax in place, 8192 rows
  softmax_rows<<<dim3(8192), blk, 0, stream>>>(S);
  // 5: O_z = P_z @ V_z == BT(A=S_z, Bt=Vt+z*4096, ldb=8192) -> O.
  //    Thin tile BN=64: 1024 blocks, ~4 blocks/CU, XCD-swz.
  gemm_bt<1, 64><<<dim3(16, 32, 2), blk, 0, stream>>>(S, Vt, O,
                                                      4096, 4096, 8192, 1024,
                                                      16777216LL, 4096LL, 4194304LL,
                                                      1.f, 0);
  // 6: out = O @ Wo^T   (M=8192, N=1024, K=1024), FP32 store.
  //    Thin tile BN=64: 1024 blocks, ~4 blocks/CU, XCD-swz.
  gemm_bt<1, 64><<<dim3(16, 64, 1), blk, 0, stream>>>(O, Wob, out,
                                                      1024, 1024, 1024, 1024,
                                                      0, 0, 0, 1.f, 1);
}

// Round 9
// 396.903 us; speedup vs baseline: 1.0573x; 1.0573x over previous
//
#include <hip/hip_runtime.h>
#include <hip/hip_bf16.h>
#include <stdint.h>

// MultiHeadedSelfAttention: B=2, L=4096, D=1024, H=1. fp32 inputs, FP32 output.
// Round 21: consolidation on measured evidence.
//  - BN=64 thin tile REVERTED (R8: occupancy 42% but PV 113µs vs 104 — MFMA
//    per barrier-pair halved; co-residency >3/CU buys nothing). BN fixed 128.
//  - Depth-3 prefetch everywhere (R4 isolated A/B on scores: 102.8 vs 105.2;
//    48KiB LDS free — measured occupancy never reaches the 32KiB cap).
//  - Swizzle pattern exactly as round-6 (best passing config, 398.7µs):
//    XCD-swz on QKp/scores/PV/final; Vt natural (lin%8=bx%8 groups panels).
//  - 4 weight casts merged into one launch (saves ~3 launch overheads).
// Pipeline:
//   0. cast x (grid 4096); cast W4 (grid 2048)
//   1. QKp = x @ [Wq;Wk]^T    (8192x2048, K=1024)  grid 1024  [<1>]
//   2. Vt  = Wv @ x^T          (1024x8192)          grid 512   [<0>]
//   3. S_z = Q_z @ Kp_z^T/32   (2x 4096x4096)       grid 2048  [<1>]
//   4. softmax rows (8192 rows)
//   5. O_z = P_z @ V_z         -> O into QKp region grid 512   [<1>]
//   6. out = O @ Wo^T -> FP32 d_out                 grid 512   [<1>]
// ws (u16): xb 8.39M | W*b 4x1.05M | QKp 16.78M | Vt 8.39M | S 33.55M
// = 71,303,168 u16 = 136 MiB (layout proven safe in prior rounds).

typedef unsigned short u16;
typedef short short8 __attribute__((ext_vector_type(8)));
typedef float f32x4 __attribute__((ext_vector_type(4)));

__device__ __forceinline__ void async_ld16(void* lds, const void* g) {
  __builtin_amdgcn_global_load_lds(
      (const __attribute__((address_space(1))) unsigned int*)g,
      (__attribute__((address_space(3))) unsigned int*)lds,
      16, 0, 0);
}

__device__ __forceinline__ u16 f2bf(float f) {  // RNE
  unsigned u = __float_as_uint(f);
  u += 0x7FFFu + ((u >> 16) & 1u);
  return (u16)(u >> 16);
}

// fp32 -> bf16, 8 elems/thread. n must be a multiple of 8 (true here).
__global__ __launch_bounds__(256)
void cast_f32_bf16(const float* __restrict__ in, u16* __restrict__ out, int n) {
  const int i = (blockIdx.x * 256 + threadIdx.x) * 8;
  if (i >= n) return;
  float4 a = ((const float4*)(in + i))[0];
  float4 b = ((const float4*)(in + i))[1];
  uint4 o;
  o.x = (unsigned)f2bf(a.x) | ((unsigned)f2bf(a.y) << 16);
  o.y = (unsigned)f2bf(a.z) | ((unsigned)f2bf(a.w) << 16);
  o.z = (unsigned)f2bf(b.x) | ((unsigned)f2bf(b.y) << 16);
  o.w = (unsigned)f2bf(b.z) | ((unsigned)f2bf(b.w) << 16);
  *(uint4*)(out + i) = o;
}

// 4 weight matrices (each n = 1<<20 fp32) -> one contiguous bf16 region.
// grid 2048 x 256: idx = gid*8 in [0, 4M); which = idx>>20 (block-uniform).
__global__ __launch_bounds__(256)
void cast_w4_bf16(const float* __restrict__ w0, const float* __restrict__ w1,
                  const float* __restrict__ w2, const float* __restrict__ w3,
                  u16* __restrict__ out) {
  const int idx = (blockIdx.x * 256 + threadIdx.x) * 8;
  const int which = idx >> 20;
  const int off = idx & 1048575;
  const float* src = which == 0 ? w0 : which == 1 ? w1 : which == 2 ? w2 : w3;
  float4 a = ((const float4*)(src + off))[0];
  float4 b = ((const float4*)(src + off))[1];
  uint4 o;
  o.x = (unsigned)f2bf(a.x) | ((unsigned)f2bf(a.y) << 16);
  o.y = (unsigned)f2bf(a.z) | ((unsigned)f2bf(a.w) << 16);
  o.z = (unsigned)f2bf(b.x) | ((unsigned)f2bf(b.y) << 16);
  o.w = (unsigned)f2bf(b.z) | ((unsigned)f2bf(b.w) << 16);
  *(uint4*)(out + idx) = o;
}

#define BM 128
#define BN 128
#define BK 32

// C(MxN, ldc) = scale * A(MxK, lda) @ Bt(NxK, ldb)^T. A,Bt bf16; fp32 accum.
// Triple-buffered LDS (3x16KB), depth-3 prefetch, counted vmcnt(8/4/0).
// 4 waves in 2x2; wave tile 64x64 (4x4 fragments of 16).
// XSWZ=1 adds bijective XCD block swizzle (needs nwg % 8 == 0).
// Buffer discipline (R4/R8-proven): stage(kt)->buf[kt%3]; top of kt:
// counted vmcnt + barrier; reads+MFMA; end barrier; stage(kt+3) into the
// same-index buffer just fully read.
template <int XSWZ>
__global__ __launch_bounds__(256)
void gemm_bt(const u16* __restrict__ A, const u16* __restrict__ Bt,
             void* __restrict__ Cv, int K, int lda, int ldb, int ldc,
             long long sAz, long long sBz, long long sCz,
             float scale, int store_f32) {
  __shared__ u16 As[3][BM * BK];
  __shared__ u16 Bs[3][BN * BK];

  int bx, by, bz;
  if constexpr (XSWZ) {
    const int gx = gridDim.x, gy = gridDim.y;
    const int nwg = gx * gy * gridDim.z;
    const int lin = (blockIdx.z * gy + blockIdx.y) * gx + blockIdx.x;
    const int chunk = nwg >> 3;
    const int swz = (lin & 7) * chunk + (lin >> 3);
    bx = swz % gx;
    const int t1 = swz / gx;
    by = t1 % gy;
    bz = t1 / gy;
  } else {
    bx = blockIdx.x; by = blockIdx.y; bz = blockIdx.z;
  }

  A  += (long long)bz * sAz;
  Bt += (long long)bz * sBz;

  const int tid  = threadIdx.x;
  const int wave = tid >> 6;
  const int lane = tid & 63;
  const int wm   = wave >> 1;      // 0..1: wave row in 2x2
  const int wn   = wave & 1;       // 0..1: wave col
  const int r15  = lane & 15;
  const int q4   = lane >> 4;      // 0..3

  const int tileM = by * BM;
  const int tileN = bx * BN;

  const int srow = tid >> 2;                        // 0..63
  const int scol = ((tid & 3) ^ (srow & 3)) * 8;    // pre-swizzled source col

  const u16* Aptr = A + (long long)tileM * lda + scol;
  const u16* Bptr = Bt + (long long)tileN * ldb + scol;

  // stage K-tile kt into buf[kt%3] (4 x global_load_lds, linear LDS dest).
  auto stage = [&](int kt) {
    const int b = kt % 3;
    const int k0 = kt * BK;
    u16* as = &As[b][tid * 8];
    u16* bs = &Bs[b][tid * 8];
    async_ld16(as,        Aptr + (long long)srow * lda + k0);
    async_ld16(as + 2048, Aptr + (long long)(srow + 64) * lda + k0);
    async_ld16(bs,        Bptr + (long long)srow * ldb + k0);
    async_ld16(bs + 2048, Bptr + (long long)(srow + 64) * ldb + k0);
  };

  f32x4 zero = {0.f, 0.f, 0.f, 0.f};
  f32x4 acc[4][4];
#pragma unroll
  for (int i = 0; i < 4; ++i)
#pragma unroll
    for (int j = 0; j < 4; ++j) acc[i][j] = zero;

  // read col-chunk (permutation matching the staged layout)
  const int csw = ((q4 ^ (r15 & 3)) * 8);

  const int NT = K / BK;
  stage(0);
  if (NT > 1) stage(1);
  if (NT > 2) stage(2);

  for (int kt = 0; kt < NT; ++kt) {
    const int rem = NT - 1 - kt;
    if (rem >= 2)      asm volatile("s_waitcnt vmcnt(8)" ::: "memory");
    else if (rem == 1) asm volatile("s_waitcnt vmcnt(4)" ::: "memory");
    else               asm volatile("s_waitcnt vmcnt(0)" ::: "memory");
    __builtin_amdgcn_s_barrier();

    const int b = kt % 3;
    const u16* as = &As[b][0];
    const u16* bs = &Bs[b][0];

    short8 af[4], bf[4];
#pragma unroll
    for (int i = 0; i < 4; ++i)
      af[i] = *(const short8*)&as[(wm * 64 + i * 16 + r15) * BK + csw];
#pragma unroll
    for (int i = 0; i < 4; ++i)
      bf[i] = *(const short8*)&bs[(wn * 64 + i * 16 + r15) * BK + csw];

    __builtin_amdgcn_s_setprio(1);
#pragma unroll
    for (int i = 0; i < 4; ++i)
#pragma unroll
      for (int j = 0; j < 4; ++j)
        acc[i][j] = __builtin_amdgcn_mfma_f32_16x16x32_bf16(af[i], bf[j], acc[i][j], 0, 0, 0);
    __builtin_amdgcn_s_setprio(0);

    __builtin_amdgcn_s_barrier();
    if (kt + 3 < NT) stage(kt + 3);   // into buf[kt%3], fully read past barrier
  }

  // epilogue: C/D layout col = lane&15, row = q4*4 + reg  [e2e-verified]
#pragma unroll
  for (int i = 0; i < 4; ++i) {
#pragma unroll
    for (int j = 0; j < 4; ++j) {
      const int col = tileN + wn * 64 + j * 16 + r15;
#pragma unroll
      for (int r = 0; r < 4; ++r) {
        const int row = tileM + wm * 64 + i * 16 + q4 * 4 + r;
        const long long idx = (long long)bz * sCz + (long long)row * ldc + col;
        const float val = acc[i][j][r] * scale;
        if (store_f32) ((float*)Cv)[idx] = val;
        else           ((u16*)Cv)[idx] = f2bf(val);
      }
    }
  }
}

// In-place row softmax over 4096 bf16 columns. grid = rows, block = 256.
__global__ __launch_bounds__(256)
void softmax_rows(u16* __restrict__ S) {
  const int tid = threadIdx.x;
  u16* rp = S + (long long)blockIdx.x * 4096;

  uint4 a = ((const uint4*)rp)[tid * 2];
  uint4 b = ((const uint4*)rp)[tid * 2 + 1];
  unsigned w[8] = {a.x, a.y, a.z, a.w, b.x, b.y, b.z, b.w};
  float v[16];
#pragma unroll
  for (int i = 0; i < 8; ++i) {
    v[2 * i]     = __uint_as_float(w[i] << 16);
    v[2 * i + 1] = __uint_as_float(w[i] & 0xFFFF0000u);
  }

  float m = v[0];
#pragma unroll
  for (int i = 1; i < 16; ++i) m = fmaxf(m, v[i]);
#pragma unroll
  for (int o = 32; o > 0; o >>= 1) m = fmaxf(m, __shfl_xor(m, o));
  __shared__ float redm[4];
  __shared__ float reds[4];
  const int wave = tid >> 6;
  if ((tid & 63) == 0) redm[wave] = m;
  __syncthreads();
  m = fmaxf(fmaxf(redm[0], redm[1]), fmaxf(redm[2], redm[3]));

  float s = 0.f;
#pragma unroll
  for (int i = 0; i < 16; ++i) {
    v[i] = __expf(v[i] - m);
    s += v[i];
  }
#pragma unroll
  for (int o = 32; o > 0; o >>= 1) s += __shfl_xor(s, o);
  if ((tid & 63) == 0) reds[wave] = s;
  __syncthreads();
  s = (reds[0] + reds[1]) + (reds[2] + reds[3]);
  const float inv = 1.0f / s;

#pragma unroll
  for (int i = 0; i < 8; ++i)
    w[i] = (unsigned)f2bf(v[2 * i] * inv) | ((unsigned)f2bf(v[2 * i + 1] * inv) << 16);
  uint4 oa = {w[0], w[1], w[2], w[3]};
  uint4 ob = {w[4], w[5], w[6], w[7]};
  ((uint4*)rp)[tid * 2] = oa;
  ((uint4*)rp)[tid * 2 + 1] = ob;
}

extern "C" void kernel_launch(void* const* d_in, const int* in_sizes, int n_in,
                              void* d_out, int out_size, void* d_ws, size_t ws_size,
                              hipStream_t stream) {
  const float* x  = (const float*)d_in[0];   // (2,4096,1024) fp32, batch-major
  const float* Wq = (const float*)d_in[1];   // (1024,1024) fp32 (out,in)
  const float* Wk = (const float*)d_in[2];
  const float* Wv = (const float*)d_in[3];
  const float* Wo = (const float*)d_in[4];
  float* out = (float*)d_out;                // (2,4096,1024) FP32

  // ws layout (u16 units) — 136 MiB total
  u16* xb  = (u16*)d_ws;                     // 8192x1024
  u16* Wqb = xb  + 8388608;                  // 1024x1024
  u16* Wkb = Wqb + 1048576;                  // contiguous after Wqb
  u16* Wvb = Wkb + 1048576;
  u16* Wob = Wvb + 1048576;
  u16* QKp = Wob + 1048576;                  // 8192x2048: Q cols 0-1023, Kp 1024+
  u16* Vt  = QKp + 16777216;                 // 1024x8192 (Vt[e][b*4096+l])
  u16* S   = Vt  + 8388608;                  // 2 x 4096x4096
  u16* O   = QKp;                            // alias: QKp dead after scores GEMM

  const dim3 blk(256);

  // 0: casts (x + all four W in one launch)
  cast_f32_bf16<<<dim3(4096), blk, 0, stream>>>(x, xb, 8388608);
  cast_w4_bf16<<<dim3(2048), blk, 0, stream>>>(Wq, Wk, Wv, Wo, Wqb);

  // 1: QKp = x @ [Wq;Wk]^T   (M=8192, N=2048, K=1024), 1024 blocks, XCD-swz
  gemm_bt<1><<<dim3(16, 64, 1), blk, 0, stream>>>(xb, Wqb, QKp,
                                                  1024, 1024, 1024, 2048,
                                                  0, 0, 0, 1.f, 0);
  // 2: Vt = Wv@x^T   (M=1024, N=8192, K=1024) -> ldc=8192, 512 blocks.
  //    NO swizzle: natural lin%8=bx%8 already groups same-B-panel per XCD.
  gemm_bt<0><<<dim3(64, 8, 1), blk, 0, stream>>>(Wvb, xb, Vt,
                                                 1024, 1024, 1024, 8192,
                                                 0, 0, 0, 1.f, 0);
  // 3: S_z = Q_z @ Kp_z^T / 32   (M=N=4096, K=1024), z=2 — 2048 blocks, XCD-swz
  gemm_bt<1><<<dim3(32, 32, 2), blk, 0, stream>>>(QKp, QKp + 1024, S,
                                                  1024, 2048, 2048, 4096,
                                                  8388608LL, 8388608LL, 16777216LL,
                                                  0.03125f, 0);
  // 4: softmax in place, 8192 rows
  softmax_rows<<<dim3(8192), blk, 0, stream>>>(S);
  // 5: O_z = P_z @ V_z == BT(A=S_z, Bt=Vt+z*4096, ldb=8192) -> O, 512 blocks,
  //    XCD-swz (8 consecutive blocks share a 1MB S-panel).
  gemm_bt<1><<<dim3(8, 32, 2), blk, 0, stream>>>(S, Vt, O,
                                                 4096, 4096, 8192, 1024,
                                                 16777216LL, 4096LL, 4194304LL,
                                                 1.f, 0);
  // 6: out = O @ Wo^T   (M=8192, N=1024, K=1024), FP32 store, 512 blocks,
  //    XCD-swz (8 consecutive blocks share a 1MB O-panel).
  gemm_bt<1><<<dim3(8, 64, 1), blk, 0, stream>>>(O, Wob, out,
                                                 1024, 1024, 1024, 1024,
                                                 0, 0, 0, 1.f, 1);
}

// Round 10
// 389.774 us; speedup vs baseline: 1.0767x; 1.0183x over previous
//
#include <hip/hip_runtime.h>
#include <hip/hip_bf16.h>
#include <stdint.h>

// MultiHeadedSelfAttention: B=2, L=4096, D=1024, H=1. fp32 inputs, FP32 output.
// Round 22: scores GEMM moves to a fine-phase 256x256 kernel (gemm256_8ph):
// BK=32, 3 rotating LDS buffers (96KiB — provably race-free at prefetch
// depth 2, unlike BK=64 dbuf), per-K-tile: 2 phases x {ds_reads + 2-load
// stage + barrier + setprio 16-MFMA + barrier}, counted vmcnt(4) (0 only on
// the last tile), bank-neutral chunk permutation (inverse-swizzled global
// source, swizzled ds_read), bijective XCD swizzle. 8 waves (2Mx4N), wave
// tile 128x64, acc[8][4] = 128 VGPR -> 2 waves/SIMD.
// Everything else = round-9 best (396.9us): depth-3 gemm_bt, cast merge.
// Pipeline:
//   0. cast x (grid 4096); cast W4 (grid 2048)
//   1. QKp = x @ [Wq;Wk]^T    (8192x2048, K=1024)  grid 1024  [gemm_bt<1>]
//   2. Vt  = Wv @ x^T          (1024x8192)          grid 512   [gemm_bt<0>]
//   3. S_z = Q_z @ Kp_z^T/32   (2x 4096x4096)       grid 512   [gemm256_8ph]
//   4. softmax rows (8192 rows)
//   5. O_z = P_z @ V_z         -> O into QKp region grid 512   [gemm_bt<1>]
//   6. out = O @ Wo^T -> FP32 d_out                 grid 512   [gemm_bt<1>]
// ws (u16): xb 8.39M | W*b 4x1.05M | QKp 16.78M | Vt 8.39M | S 33.55M
// = 71,303,168 u16 = 136 MiB (layout proven safe in prior rounds).

typedef unsigned short u16;
typedef short short8 __attribute__((ext_vector_type(8)));
typedef float f32x4 __attribute__((ext_vector_type(4)));

__device__ __forceinline__ void async_ld16(void* lds, const void* g) {
  __builtin_amdgcn_global_load_lds(
      (const __attribute__((address_space(1))) unsigned int*)g,
      (__attribute__((address_space(3))) unsigned int*)lds,
      16, 0, 0);
}

__device__ __forceinline__ u16 f2bf(float f) {  // RNE
  unsigned u = __float_as_uint(f);
  u += 0x7FFFu + ((u >> 16) & 1u);
  return (u16)(u >> 16);
}

// fp32 -> bf16, 8 elems/thread. n must be a multiple of 8 (true here).
__global__ __launch_bounds__(256)
void cast_f32_bf16(const float* __restrict__ in, u16* __restrict__ out, int n) {
  const int i = (blockIdx.x * 256 + threadIdx.x) * 8;
  if (i >= n) return;
  float4 a = ((const float4*)(in + i))[0];
  float4 b = ((const float4*)(in + i))[1];
  uint4 o;
  o.x = (unsigned)f2bf(a.x) | ((unsigned)f2bf(a.y) << 16);
  o.y = (unsigned)f2bf(a.z) | ((unsigned)f2bf(a.w) << 16);
  o.z = (unsigned)f2bf(b.x) | ((unsigned)f2bf(b.y) << 16);
  o.w = (unsigned)f2bf(b.z) | ((unsigned)f2bf(b.w) << 16);
  *(uint4*)(out + i) = o;
}

// 4 weight matrices (each n = 1<<20 fp32) -> one contiguous bf16 region.
__global__ __launch_bounds__(256)
void cast_w4_bf16(const float* __restrict__ w0, const float* __restrict__ w1,
                  const float* __restrict__ w2, const float* __restrict__ w3,
                  u16* __restrict__ out) {
  const int idx = (blockIdx.x * 256 + threadIdx.x) * 8;
  const int which = idx >> 20;
  const int off = idx & 1048575;
  const float* src = which == 0 ? w0 : which == 1 ? w1 : which == 2 ? w2 : w3;
  float4 a = ((const float4*)(src + off))[0];
  float4 b = ((const float4*)(src + off))[1];
  uint4 o;
  o.x = (unsigned)f2bf(a.x) | ((unsigned)f2bf(a.y) << 16);
  o.y = (unsigned)f2bf(a.z) | ((unsigned)f2bf(a.w) << 16);
  o.z = (unsigned)f2bf(b.x) | ((unsigned)f2bf(b.y) << 16);
  o.w = (unsigned)f2bf(b.z) | ((unsigned)f2bf(b.w) << 16);
  *(uint4*)(out + idx) = o;
}

#define BM 128
#define BN 128
#define BK 32

// ---- 128^2 workhorse (round-9 form): triple-buffered, depth-3, vmcnt(8/4/0).
template <int XSWZ>
__global__ __launch_bounds__(256)
void gemm_bt(const u16* __restrict__ A, const u16* __restrict__ Bt,
             void* __restrict__ Cv, int K, int lda, int ldb, int ldc,
             long long sAz, long long sBz, long long sCz,
             float scale, int store_f32) {
  __shared__ u16 As[3][BM * BK];
  __shared__ u16 Bs[3][BN * BK];

  int bx, by, bz;
  if constexpr (XSWZ) {
    const int gx = gridDim.x, gy = gridDim.y;
    const int nwg = gx * gy * gridDim.z;
    const int lin = (blockIdx.z * gy + blockIdx.y) * gx + blockIdx.x;
    const int chunk = nwg >> 3;
    const int swz = (lin & 7) * chunk + (lin >> 3);
    bx = swz % gx;
    const int t1 = swz / gx;
    by = t1 % gy;
    bz = t1 / gy;
  } else {
    bx = blockIdx.x; by = blockIdx.y; bz = blockIdx.z;
  }

  A  += (long long)bz * sAz;
  Bt += (long long)bz * sBz;

  const int tid  = threadIdx.x;
  const int wave = tid >> 6;
  const int lane = tid & 63;
  const int wm   = wave >> 1;
  const int wn   = wave & 1;
  const int r15  = lane & 15;
  const int q4   = lane >> 4;

  const int tileM = by * BM;
  const int tileN = bx * BN;

  const int srow = tid >> 2;
  const int scol = ((tid & 3) ^ (srow & 3)) * 8;

  const u16* Aptr = A + (long long)tileM * lda + scol;
  const u16* Bptr = Bt + (long long)tileN * ldb + scol;

  auto stage = [&](int kt) {
    const int b = kt % 3;
    const int k0 = kt * BK;
    u16* as = &As[b][tid * 8];
    u16* bs = &Bs[b][tid * 8];
    async_ld16(as,        Aptr + (long long)srow * lda + k0);
    async_ld16(as + 2048, Aptr + (long long)(srow + 64) * lda + k0);
    async_ld16(bs,        Bptr + (long long)srow * ldb + k0);
    async_ld16(bs + 2048, Bptr + (long long)(srow + 64) * ldb + k0);
  };

  f32x4 zero = {0.f, 0.f, 0.f, 0.f};
  f32x4 acc[4][4];
#pragma unroll
  for (int i = 0; i < 4; ++i)
#pragma unroll
    for (int j = 0; j < 4; ++j) acc[i][j] = zero;

  const int csw = ((q4 ^ (r15 & 3)) * 8);

  const int NT = K / BK;
  stage(0);
  if (NT > 1) stage(1);
  if (NT > 2) stage(2);

  for (int kt = 0; kt < NT; ++kt) {
    const int rem = NT - 1 - kt;
    if (rem >= 2)      asm volatile("s_waitcnt vmcnt(8)" ::: "memory");
    else if (rem == 1) asm volatile("s_waitcnt vmcnt(4)" ::: "memory");
    else               asm volatile("s_waitcnt vmcnt(0)" ::: "memory");
    __builtin_amdgcn_s_barrier();

    const int b = kt % 3;
    const u16* as = &As[b][0];
    const u16* bs = &Bs[b][0];

    short8 af[4], bf[4];
#pragma unroll
    for (int i = 0; i < 4; ++i)
      af[i] = *(const short8*)&as[(wm * 64 + i * 16 + r15) * BK + csw];
#pragma unroll
    for (int i = 0; i < 4; ++i)
      bf[i] = *(const short8*)&bs[(wn * 64 + i * 16 + r15) * BK + csw];

    __builtin_amdgcn_s_setprio(1);
#pragma unroll
    for (int i = 0; i < 4; ++i)
#pragma unroll
      for (int j = 0; j < 4; ++j)
        acc[i][j] = __builtin_amdgcn_mfma_f32_16x16x32_bf16(af[i], bf[j], acc[i][j], 0, 0, 0);
    __builtin_amdgcn_s_setprio(0);

    __builtin_amdgcn_s_barrier();
    if (kt + 3 < NT) stage(kt + 3);
  }

#pragma unroll
  for (int i = 0; i < 4; ++i) {
#pragma unroll
    for (int j = 0; j < 4; ++j) {
      const int col = tileN + wn * 64 + j * 16 + r15;
#pragma unroll
      for (int r = 0; r < 4; ++r) {
        const int row = tileM + wm * 64 + i * 16 + q4 * 4 + r;
        const long long idx = (long long)bz * sCz + (long long)row * ldc + col;
        const float val = acc[i][j][r] * scale;
        if (store_f32) ((float*)Cv)[idx] = val;
        else           ((u16*)Cv)[idx] = f2bf(val);
      }
    }
  }
}

// ---------------------------------------------------------------------------
// 256x256 fine-phase GEMM (scores): BK=32, 3 rotating buffers (96 KiB),
// 8 waves (2Mx4N), wave tile 128x64, acc[8][4]. Per K-tile t:
//   vmcnt(4)[last:0]; barrier;
//   ph0: ds_read bf[4]+af[4] (8xb128); stage A(t+2) (2 loads); barrier;
//        setprio(1); 16 MFMA (rows 0-63); setprio(0); barrier;
//   ph1: ds_read af[4] (+64 rows);     stage B(t+2) (2 loads); barrier;
//        setprio(1); 16 MFMA (rows 64-127); setprio(0); barrier;
// Race-free: tile τ staged during τ-2 into buf[τ%3], which was freed by
// τ-1's reads one barrier earlier; vmcnt(4) retires exactly tile t's 4
// loads (FIFO), t+1's stay in flight — never drained mid-loop.
// Bank permutation: LDS[row][c] holds global chunk (c-(row>>1))&3; read at
// c=(q4+(r15>>1))&3 -> 2-way bank aliasing (free). Staged via per-thread
// inverse-swizzled global column; LDS dest stays linear (= tid*16B).
// ---------------------------------------------------------------------------
__global__ __launch_bounds__(512, 2)
void gemm256_8ph(const u16* __restrict__ A, const u16* __restrict__ Bt,
                 u16* __restrict__ C, int K, int lda, int ldb, int ldc,
                 long long sAz, long long sBz, long long sCz, float scale) {
  __shared__ u16 smem[49152];  // 3 x (A 256x32 + B 256x32) u16 = 96 KiB

  // bijective XCD swizzle (nwg = 512, %8 == 0)
  const int gx = gridDim.x, gy = gridDim.y;
  const int nwg = gx * gy * gridDim.z;
  const int lin = (blockIdx.z * gy + blockIdx.y) * gx + blockIdx.x;
  const int chunk = nwg >> 3;
  const int swz = (lin & 7) * chunk + (lin >> 3);
  const int bx = swz % gx;
  const int t1 = swz / gx;
  const int by = t1 % gy;
  const int bz = t1 / gy;

  A  += (long long)bz * sAz;
  Bt += (long long)bz * sBz;
  const long long cbase = (long long)bz * sCz;

  const int tid  = threadIdx.x;
  const int wid  = tid >> 6;
  const int lane = tid & 63;
  const int wm   = wid >> 2;       // 0..1  (M half)
  const int wn   = wid & 3;        // 0..3  (N quarter)
  const int r15  = lane & 15;
  const int q4   = lane >> 4;

  const int tileM = by * 256;
  const int tileN = bx * 256;

  // staging: thread -> (row = tid>>2 in 0..127, chunk slot = tid&3).
  // LDS slot (row, c) must hold global chunk (c - (row>>1)) & 3.
  const int sr  = tid >> 2;
  const int gc8 = ((((tid & 3) - ((tid >> 3) & 3)) & 3)) * 8;

  const u16* Asrc = A  + (long long)(tileM + sr) * lda + gc8;
  const u16* Bsrc = Bt + (long long)(tileN + sr) * ldb + gc8;

  auto stage2A = [&](int kt) {
    u16* d = &smem[(kt % 3) * 16384 + tid * 8];
    async_ld16(d,        Asrc + kt * 32);
    async_ld16(d + 4096, Asrc + (long long)128 * lda + kt * 32);
  };
  auto stage2B = [&](int kt) {
    u16* d = &smem[(kt % 3) * 16384 + 8192 + tid * 8];
    async_ld16(d,        Bsrc + kt * 32);
    async_ld16(d + 4096, Bsrc + (long long)128 * ldb + kt * 32);
  };

  // read chunk: c = (q4 + (r15>>1)) & 3  (per-lane constant; row-base ≡ 0 mod 4)
  const int csw = (((q4 + (r15 >> 1)) & 3)) * 8;

  f32x4 acc[8][4];
#pragma unroll
  for (int i = 0; i < 8; ++i)
#pragma unroll
    for (int j = 0; j < 4; ++j) acc[i][j] = (f32x4){0.f, 0.f, 0.f, 0.f};

  const int NT = K >> 5;   // BK = 32

  stage2A(0); stage2B(0);
  if (NT > 1) { stage2A(1); stage2B(1); }

  for (int t = 0; t < NT; ++t) {
    if (t + 1 < NT) asm volatile("s_waitcnt vmcnt(4)" ::: "memory");
    else            asm volatile("s_waitcnt vmcnt(0)" ::: "memory");
    __builtin_amdgcn_s_barrier();

    const u16* bufA = &smem[(t % 3) * 16384];
    const u16* bufB = bufA + 8192;

    // ---- phase 0: B (whole tile) + A rows 0-63 of this wave's half
    short8 bf[4], af[4];
#pragma unroll
    for (int j = 0; j < 4; ++j)
      bf[j] = *(const short8*)&bufB[(wn * 64 + j * 16 + r15) * 32 + csw];
#pragma unroll
    for (int i = 0; i < 4; ++i)
      af[i] = *(const short8*)&bufA[(wm * 128 + i * 16 + r15) * 32 + csw];
    if (t + 2 < NT) stage2A(t + 2);
    __builtin_amdgcn_s_barrier();

    __builtin_amdgcn_s_setprio(1);
#pragma unroll
    for (int i = 0; i < 4; ++i)
#pragma unroll
      for (int j = 0; j < 4; ++j)
        acc[i][j] = __builtin_amdgcn_mfma_f32_16x16x32_bf16(af[i], bf[j], acc[i][j], 0, 0, 0);
    __builtin_amdgcn_s_setprio(0);
    __builtin_amdgcn_s_barrier();

    // ---- phase 1: A rows 64-127
#pragma unroll
    for (int i = 0; i < 4; ++i)
      af[i] = *(const short8*)&bufA[(wm * 128 + 64 + i * 16 + r15) * 32 + csw];
    if (t + 2 < NT) stage2B(t + 2);
    __builtin_amdgcn_s_barrier();

    __builtin_amdgcn_s_setprio(1);
#pragma unroll
    for (int i = 0; i < 4; ++i)
#pragma unroll
      for (int j = 0; j < 4; ++j)
        acc[4 + i][j] = __builtin_amdgcn_mfma_f32_16x16x32_bf16(af[i], bf[j], acc[4 + i][j], 0, 0, 0);
    __builtin_amdgcn_s_setprio(0);
    __builtin_amdgcn_s_barrier();
  }

  // epilogue: col = lane&15, row = q4*4 + reg  [e2e-verified mapping]
  const int crow = tileM + wm * 128 + q4 * 4;
  const int ccol = tileN + wn * 64 + r15;
#pragma unroll
  for (int mi = 0; mi < 8; ++mi)
#pragma unroll
    for (int nj = 0; nj < 4; ++nj)
#pragma unroll
      for (int r = 0; r < 4; ++r) {
        const long long row = crow + mi * 16 + r;
        C[cbase + row * ldc + (ccol + nj * 16)] = f2bf(acc[mi][nj][r] * scale);
      }
}

// In-place row softmax over 4096 bf16 columns. grid = rows, block = 256.
__global__ __launch_bounds__(256)
void softmax_rows(u16* __restrict__ S) {
  const int tid = threadIdx.x;
  u16* rp = S + (long long)blockIdx.x * 4096;

  uint4 a = ((const uint4*)rp)[tid * 2];
  uint4 b = ((const uint4*)rp)[tid * 2 + 1];
  unsigned w[8] = {a.x, a.y, a.z, a.w, b.x, b.y, b.z, b.w};
  float v[16];
#pragma unroll
  for (int i = 0; i < 8; ++i) {
    v[2 * i]     = __uint_as_float(w[i] << 16);
    v[2 * i + 1] = __uint_as_float(w[i] & 0xFFFF0000u);
  }

  float m = v[0];
#pragma unroll
  for (int i = 1; i < 16; ++i) m = fmaxf(m, v[i]);
#pragma unroll
  for (int o = 32; o > 0; o >>= 1) m = fmaxf(m, __shfl_xor(m, o));
  __shared__ float redm[4];
  __shared__ float reds[4];
  const int wave = tid >> 6;
  if ((tid & 63) == 0) redm[wave] = m;
  __syncthreads();
  m = fmaxf(fmaxf(redm[0], redm[1]), fmaxf(redm[2], redm[3]));

  float s = 0.f;
#pragma unroll
  for (int i = 0; i < 16; ++i) {
    v[i] = __expf(v[i] - m);
    s += v[i];
  }
#pragma unroll
  for (int o = 32; o > 0; o >>= 1) s += __shfl_xor(s, o);
  if ((tid & 63) == 0) reds[wave] = s;
  __syncthreads();
  s = (reds[0] + reds[1]) + (reds[2] + reds[3]);
  const float inv = 1.0f / s;

#pragma unroll
  for (int i = 0; i < 8; ++i)
    w[i] = (unsigned)f2bf(v[2 * i] * inv) | ((unsigned)f2bf(v[2 * i + 1] * inv) << 16);
  uint4 oa = {w[0], w[1], w[2], w[3]};
  uint4 ob = {w[4], w[5], w[6], w[7]};
  ((uint4*)rp)[tid * 2] = oa;
  ((uint4*)rp)[tid * 2 + 1] = ob;
}

extern "C" void kernel_launch(void* const* d_in, const int* in_sizes, int n_in,
                              void* d_out, int out_size, void* d_ws, size_t ws_size,
                              hipStream_t stream) {
  const float* x  = (const float*)d_in[0];   // (2,4096,1024) fp32, batch-major
  const float* Wq = (const float*)d_in[1];   // (1024,1024) fp32 (out,in)
  const float* Wk = (const float*)d_in[2];
  const float* Wv = (const float*)d_in[3];
  const float* Wo = (const float*)d_in[4];
  float* out = (float*)d_out;                // (2,4096,1024) FP32

  // ws layout (u16 units) — 136 MiB total
  u16* xb  = (u16*)d_ws;                     // 8192x1024
  u16* Wqb = xb  + 8388608;                  // 1024x1024
  u16* Wkb = Wqb + 1048576;                  // contiguous after Wqb
  u16* Wvb = Wkb + 1048576;
  u16* Wob = Wvb + 1048576;
  u16* QKp = Wob + 1048576;                  // 8192x2048: Q cols 0-1023, Kp 1024+
  u16* Vt  = QKp + 16777216;                 // 1024x8192 (Vt[e][b*4096+l])
  u16* S   = Vt  + 8388608;                  // 2 x 4096x4096
  u16* O   = QKp;                            // alias: QKp dead after scores GEMM

  const dim3 blk(256);

  // 0: casts (x + all four W in one launch)
  cast_f32_bf16<<<dim3(4096), blk, 0, stream>>>(x, xb, 8388608);
  cast_w4_bf16<<<dim3(2048), blk, 0, stream>>>(Wq, Wk, Wv, Wo, Wqb);

  // 1: QKp = x @ [Wq;Wk]^T   (M=8192, N=2048, K=1024), 1024 blocks, XCD-swz
  gemm_bt<1><<<dim3(16, 64, 1), blk, 0, stream>>>(xb, Wqb, QKp,
                                                  1024, 1024, 1024, 2048,
                                                  0, 0, 0, 1.f, 0);
  // 2: Vt = Wv@x^T   (M=1024, N=8192, K=1024) -> ldc=8192, 512 blocks, natural
  gemm_bt<0><<<dim3(64, 8, 1), blk, 0, stream>>>(Wvb, xb, Vt,
                                                 1024, 1024, 1024, 8192,
                                                 0, 0, 0, 1.f, 0);
  // 3: S_z = Q_z @ Kp_z^T / 32  (M=N=4096, K=1024), z=2 — 256^2 fine-phase,
  //    grid (16,16,2) = 512 blocks x 512 threads.
  gemm256_8ph<<<dim3(16, 16, 2), dim3(512), 0, stream>>>(
      QKp, QKp + 1024, S, 1024, 2048, 2048, 4096,
      8388608LL, 8388608LL, 16777216LL, 0.03125f);
  // 4: softmax in place, 8192 rows
  softmax_rows<<<dim3(8192), blk, 0, stream>>>(S);
  // 5: O_z = P_z @ V_z == BT(A=S_z, Bt=Vt+z*4096, ldb=8192) -> O, XCD-swz
  gemm_bt<1><<<dim3(8, 32, 2), blk, 0, stream>>>(S, Vt, O,
                                                 4096, 4096, 8192, 1024,
                                                 16777216LL, 4096LL, 4194304LL,
                                                 1.f, 0);
  // 6: out = O @ Wo^T   (M=8192, N=1024, K=1024), FP32 store, XCD-swz
  gemm_bt<1><<<dim3(8, 64, 1), blk, 0, stream>>>(O, Wob, out,
                                                 1024, 1024, 1024, 1024,
                                                 0, 0, 0, 1.f, 1);
}